// Round 4
// baseline (1678.085 us; speedup 1.0000x reference)
//
#include <hip/hip_runtime.h>

// Linear attention (non-causal), N=4, L=8192, H=16, D=M=64, fp32.
//   fm(x) = elu(x)+1
//   KV[n,h,d,m] = sum_s fm(K[n,s,h,d]) * V[n,s,h,m]
//   Ksum[n,h,d] = sum_s fm(K[n,s,h,d])
//   z[n,l,h]    = 1/(fm(Q[n,l,h,:]) . Ksum[n,h,:]) + 1e-10
//   out[n,l,h,m]= z * sum_d fm(Q[n,l,h,d]) * KV[n,h,d,m]
//
// R3 post-mortem: LDS wave-instruction count is the wall (per-CU shared pipe,
// ~12cyc per ds_read_b128). R4: pass1 = 1-wave blocks, V direct-from-global
// (zero LDS), K via 512B LDS window (fm once), 4x8 patch, no barriers.
// pass2 = 8x8 patch, Q direct-from-global (fm dup x8), KV via LDS.

#define EPSV      1e-10f
#define L_SEQ     8192
#define NH_TOT    64
#define ROWSTRIDE 1024
#define KV_STRIDE 4160
#define SLICE     (NH_TOT * KV_STRIDE)   // 266240 floats per chunk-slice
#define CH_SPLIT  32
#define RPB       256                    // s-rows per pass1 block
#define NWIN      64                     // RPB/4

__device__ __forceinline__ float fm(float x) {
    return x > 0.0f ? x + 1.0f : __expf(x);
}

// ==================== Pass 1: KV + Ksum partials ====================
// grid (2 d-half, 64 nh, 32 chunk), block 64 (one wave).
// Lane patch: 4 d-rows (within the 32-row half) x 8 m-cols. acc[4][8].
// Per 4-row window: 1 ds_write_b64 (fm'd K) + 4 ds_read_b128 + 8 global V loads.

#define P1_RANK1(KC, V0, V1, AI)                                    \
    acc[AI][0] += (KC) * (V0).x; acc[AI][1] += (KC) * (V0).y;       \
    acc[AI][2] += (KC) * (V0).z; acc[AI][3] += (KC) * (V0).w;       \
    acc[AI][4] += (KC) * (V1).x; acc[AI][5] += (KC) * (V1).y;       \
    acc[AI][6] += (KC) * (V1).z; acc[AI][7] += (KC) * (V1).w;

#define P1_WINDOW(W, CUR, NXT)                                                      \
    {                                                                               \
        const int w_ = (W);                                                         \
        const float4 k40 = *reinterpret_cast<const float4*>(&kbuf[0][dq4 * 4]);     \
        const float4 k41 = *reinterpret_cast<const float4*>(&kbuf[1][dq4 * 4]);     \
        const float4 k42 = *reinterpret_cast<const float4*>(&kbuf[2][dq4 * 4]);     \
        const float4 k43 = *reinterpret_cast<const float4*>(&kbuf[3][dq4 * 4]);     \
        if (w_ + 1 < NWIN) {                                                        \
            const size_t ro = (size_t)(w_ + 1) * (4 * ROWSTRIDE);                   \
            knx = *reinterpret_cast<const float2*>(Kst + ro);                       \
            vreg[NXT][0] = *reinterpret_cast<const float4*>(Vld + ro);                          \
            vreg[NXT][1] = *reinterpret_cast<const float4*>(Vld + ro + 4);                      \
            vreg[NXT][2] = *reinterpret_cast<const float4*>(Vld + ro + ROWSTRIDE);              \
            vreg[NXT][3] = *reinterpret_cast<const float4*>(Vld + ro + ROWSTRIDE + 4);          \
            vreg[NXT][4] = *reinterpret_cast<const float4*>(Vld + ro + 2 * ROWSTRIDE);          \
            vreg[NXT][5] = *reinterpret_cast<const float4*>(Vld + ro + 2 * ROWSTRIDE + 4);      \
            vreg[NXT][6] = *reinterpret_cast<const float4*>(Vld + ro + 3 * ROWSTRIDE);          \
            vreg[NXT][7] = *reinterpret_cast<const float4*>(Vld + ro + 3 * ROWSTRIDE + 4);      \
        }                                                                           \
        P1_RANK1(k40.x, vreg[CUR][0], vreg[CUR][1], 0)                              \
        P1_RANK1(k40.y, vreg[CUR][0], vreg[CUR][1], 1)                              \
        P1_RANK1(k40.z, vreg[CUR][0], vreg[CUR][1], 2)                              \
        P1_RANK1(k40.w, vreg[CUR][0], vreg[CUR][1], 3)                              \
        P1_RANK1(k41.x, vreg[CUR][2], vreg[CUR][3], 0)                              \
        P1_RANK1(k41.y, vreg[CUR][2], vreg[CUR][3], 1)                              \
        P1_RANK1(k41.z, vreg[CUR][2], vreg[CUR][3], 2)                              \
        P1_RANK1(k41.w, vreg[CUR][2], vreg[CUR][3], 3)                              \
        P1_RANK1(k42.x, vreg[CUR][4], vreg[CUR][5], 0)                              \
        P1_RANK1(k42.y, vreg[CUR][4], vreg[CUR][5], 1)                              \
        P1_RANK1(k42.z, vreg[CUR][4], vreg[CUR][5], 2)                              \
        P1_RANK1(k42.w, vreg[CUR][4], vreg[CUR][5], 3)                              \
        P1_RANK1(k43.x, vreg[CUR][6], vreg[CUR][7], 0)                              \
        P1_RANK1(k43.y, vreg[CUR][6], vreg[CUR][7], 1)                              \
        P1_RANK1(k43.z, vreg[CUR][6], vreg[CUR][7], 2)                              \
        P1_RANK1(k43.w, vreg[CUR][6], vreg[CUR][7], 3)                              \
        if (w_ + 1 < NWIN) {                                                        \
            const float a_ = fm(knx.x), b_ = fm(knx.y);                             \
            ks0 += a_; ks1 += b_;                                                   \
            kbuf[srow][2 * spair]     = a_;                                         \
            kbuf[srow][2 * spair + 1] = b_;                                         \
        }                                                                           \
        asm volatile("s_waitcnt lgkmcnt(0)" ::: "memory");                          \
        __builtin_amdgcn_sched_barrier(0);                                          \
    }

__global__ __launch_bounds__(64, 4) void kv_pass_kernel(
    const float* __restrict__ K, const float* __restrict__ V,
    float* __restrict__ ws, int mode)
{
    const int lane  = threadIdx.x;
    const int half  = blockIdx.x;      // 0/1: d-half
    const int nh    = blockIdx.y;
    const int chunk = blockIdx.z;
    const int n = nh >> 4, h = nh & 15;

    const int dq4 = lane >> 3;         // 0..7: d-quad within half
    const int mo  = lane & 7;          // 0..7: m-octet
    const int m0  = mo << 3;

    const int srow  = lane >> 4;       // 0..3: staging row
    const int spair = lane & 15;       // 0..15: staging float2

    __shared__ float kbuf[4][32];      // one window of fm(K) half-rows (512B)

    const size_t nbase = (size_t)n * (L_SEQ * ROWSTRIDE) + h * 64;
    const int s0 = chunk * RPB;

    const float* Kst = K + nbase + (size_t)(s0 + srow) * ROWSTRIDE + half * 32 + spair * 2;
    const float* Vld = V + nbase + (size_t)s0 * ROWSTRIDE + m0;

    float acc[4][8] = {};
    float ks0 = 0.f, ks1 = 0.f;
    float4 vreg[2][8];
    float2 knx;

    // prologue: window 0
    {
        const float2 kf = *reinterpret_cast<const float2*>(Kst);
        vreg[0][0] = *reinterpret_cast<const float4*>(Vld);
        vreg[0][1] = *reinterpret_cast<const float4*>(Vld + 4);
        vreg[0][2] = *reinterpret_cast<const float4*>(Vld + ROWSTRIDE);
        vreg[0][3] = *reinterpret_cast<const float4*>(Vld + ROWSTRIDE + 4);
        vreg[0][4] = *reinterpret_cast<const float4*>(Vld + 2 * ROWSTRIDE);
        vreg[0][5] = *reinterpret_cast<const float4*>(Vld + 2 * ROWSTRIDE + 4);
        vreg[0][6] = *reinterpret_cast<const float4*>(Vld + 3 * ROWSTRIDE);
        vreg[0][7] = *reinterpret_cast<const float4*>(Vld + 3 * ROWSTRIDE + 4);
        const float a_ = fm(kf.x), b_ = fm(kf.y);
        ks0 += a_; ks1 += b_;
        kbuf[srow][2 * spair]     = a_;
        kbuf[srow][2 * spair + 1] = b_;
    }
    asm volatile("s_waitcnt lgkmcnt(0)" ::: "memory");
    __builtin_amdgcn_sched_barrier(0);

    for (int w = 0; w < NWIN; w += 2) {
        P1_WINDOW(w,     0, 1)
        P1_WINDOW(w + 1, 1, 0)
    }

    // ksum: lanes {p, p+16, p+32, p+48} share float-pair p
    ks0 += __shfl_xor(ks0, 16); ks0 += __shfl_xor(ks0, 32);
    ks1 += __shfl_xor(ks1, 16); ks1 += __shfl_xor(ks1, 32);

    float* dst = ws + (size_t)(mode ? (chunk * NH_TOT + nh) : nh) * KV_STRIDE;
    if (mode) {
#pragma unroll
        for (int i = 0; i < 4; ++i) {
            float* p = dst + (half * 32 + dq4 * 4 + i) * 64 + m0;
            *reinterpret_cast<float4*>(p) =
                make_float4(acc[i][0], acc[i][1], acc[i][2], acc[i][3]);
            *reinterpret_cast<float4*>(p + 4) =
                make_float4(acc[i][4], acc[i][5], acc[i][6], acc[i][7]);
        }
        if (lane < 16) {
            dst[4096 + half * 32 + 2 * lane]     = ks0;
            dst[4096 + half * 32 + 2 * lane + 1] = ks1;
        }
    } else {
#pragma unroll
        for (int i = 0; i < 4; ++i)
#pragma unroll
            for (int j = 0; j < 8; ++j)
                atomicAdd(dst + (half * 32 + dq4 * 4 + i) * 64 + m0 + j, acc[i][j]);
        if (lane < 16) {
            atomicAdd(dst + 4096 + half * 32 + 2 * lane, ks0);
            atomicAdd(dst + 4096 + half * 32 + 2 * lane + 1, ks1);
        }
    }
}

// ==================== Reduce: sum CH slices into slice 0 ====================
__global__ __launch_bounds__(256) void reduce_kernel(float* __restrict__ ws, int CH)
{
    const int idx = blockIdx.x * 256 + threadIdx.x;
    float s = 0.f;
    for (int c = 0; c < CH; ++c) s += ws[(size_t)c * SLICE + idx];
    ws[idx] = s;
}

// ==================== Pass 2: out = z * (fm(Q) @ KV) ====================
// grid (64, 64 nh), block 128 (2 waves, each one 64-row l-chunk).
// Lane patch: 8 l-rows x 8 m-cols. Q direct from global (fm dup x8),
// KV + Ksum in shared LDS. z-dot is lane-local.

#define P2_OROW(QF, AI)                                                            \
    acc[AI][0] += (QF).x*b00.x + (QF).y*b10.x + (QF).z*b20.x + (QF).w*b30.x;       \
    acc[AI][1] += (QF).x*b00.y + (QF).y*b10.y + (QF).z*b20.y + (QF).w*b30.y;       \
    acc[AI][2] += (QF).x*b00.z + (QF).y*b10.z + (QF).z*b20.z + (QF).w*b30.z;       \
    acc[AI][3] += (QF).x*b00.w + (QF).y*b10.w + (QF).z*b20.w + (QF).w*b30.w;       \
    acc[AI][4] += (QF).x*b01.x + (QF).y*b11.x + (QF).z*b21.x + (QF).w*b31.x;       \
    acc[AI][5] += (QF).x*b01.y + (QF).y*b11.y + (QF).z*b21.y + (QF).w*b31.y;       \
    acc[AI][6] += (QF).x*b01.z + (QF).y*b11.z + (QF).z*b21.z + (QF).w*b31.z;       \
    acc[AI][7] += (QF).x*b01.w + (QF).y*b11.w + (QF).z*b21.w + (QF).w*b31.w;

#define P2_ROW(I, CUR)                                                             \
    {                                                                              \
        float4 qf;                                                                 \
        qf.x = fm(qreg[CUR][I].x); qf.y = fm(qreg[CUR][I].y);                      \
        qf.z = fm(qreg[CUR][I].z); qf.w = fm(qreg[CUR][I].w);                      \
        zd[I] += qf.x*ks4.x + qf.y*ks4.y + qf.z*ks4.z + qf.w*ks4.w;                \
        P2_OROW(qf, I)                                                             \
    }

#define P2_WINDOW(W, CUR, NXT)                                                     \
    {                                                                              \
        const int w_ = (W);                                                        \
        const int d_ = w_ * 4;                                                     \
        if (w_ + 1 < 16) {                                                         \
            qreg[NXT][0] = *reinterpret_cast<const float4*>(Qp + d_ + 4);                          \
            qreg[NXT][1] = *reinterpret_cast<const float4*>(Qp + d_ + 4 + ROWSTRIDE);              \
            qreg[NXT][2] = *reinterpret_cast<const float4*>(Qp + d_ + 4 + 2 * (size_t)ROWSTRIDE);  \
            qreg[NXT][3] = *reinterpret_cast<const float4*>(Qp + d_ + 4 + 3 * (size_t)ROWSTRIDE);  \
        }                                                                          \
        const float4 ks4 = *reinterpret_cast<const float4*>(&Ksl[d_]);             \
        const float4 b00 = *reinterpret_cast<const float4*>(&KVl[(d_+0)*64 + m0]);     \
        const float4 b01 = *reinterpret_cast<const float4*>(&KVl[(d_+0)*64 + m0 + 4]); \
        const float4 b10 = *reinterpret_cast<const float4*>(&KVl[(d_+1)*64 + m0]);     \
        const float4 b11 = *reinterpret_cast<const float4*>(&KVl[(d_+1)*64 + m0 + 4]); \
        const float4 b20 = *reinterpret_cast<const float4*>(&KVl[(d_+2)*64 + m0]);     \
        const float4 b21 = *reinterpret_cast<const float4*>(&KVl[(d_+2)*64 + m0 + 4]); \
        const float4 b30 = *reinterpret_cast<const float4*>(&KVl[(d_+3)*64 + m0]);     \
        const float4 b31 = *reinterpret_cast<const float4*>(&KVl[(d_+3)*64 + m0 + 4]); \
        P2_ROW(0, CUR) P2_ROW(1, CUR) P2_ROW(2, CUR) P2_ROW(3, CUR)                \
        if (w_ + 1 < 16) {                                                         \
            qreg[NXT][4] = *reinterpret_cast<const float4*>(Qp + d_ + 4 + 4 * (size_t)ROWSTRIDE);  \
            qreg[NXT][5] = *reinterpret_cast<const float4*>(Qp + d_ + 4 + 5 * (size_t)ROWSTRIDE);  \
            qreg[NXT][6] = *reinterpret_cast<const float4*>(Qp + d_ + 4 + 6 * (size_t)ROWSTRIDE);  \
            qreg[NXT][7] = *reinterpret_cast<const float4*>(Qp + d_ + 4 + 7 * (size_t)ROWSTRIDE);  \
        }                                                                          \
        P2_ROW(4, CUR) P2_ROW(5, CUR) P2_ROW(6, CUR) P2_ROW(7, CUR)                \
    }

__global__ __launch_bounds__(128, 3) void out_kernel(
    const float* __restrict__ Q, const float* __restrict__ KVg,
    float* __restrict__ out)
{
    const int t  = threadIdx.x;
    const int nh = blockIdx.y;
    const int n = nh >> 4, h = nh & 15;
    const int wid  = t >> 6;
    const int lane = t & 63;

    __shared__ float KVl[4096];
    __shared__ float Ksl[64];

    const float* kvrow = KVg + (size_t)nh * KV_STRIDE;
#pragma unroll
    for (int j = 0; j < 8; ++j)
        *reinterpret_cast<float4*>(&KVl[j * 512 + t * 4]) =
            *reinterpret_cast<const float4*>(kvrow + j * 512 + t * 4);
    if (t < 16)
        *reinterpret_cast<float4*>(&Ksl[t * 4]) =
            *reinterpret_cast<const float4*>(kvrow + 4096 + t * 4);
    __syncthreads();

    const int lq = lane >> 3;          // 0..7: row octet
    const int mo = lane & 7;           // 0..7: m octet
    const int m0 = mo << 3;
    const int l0 = (blockIdx.x * 2 + wid) * 64 + lq * 8;
    const float* Qp = Q + ((size_t)n * L_SEQ + l0) * ROWSTRIDE + h * 64;

    float acc[8][8] = {};
    float zd[8] = {};
    float4 qreg[2][8];

#pragma unroll
    for (int i = 0; i < 8; ++i)
        qreg[0][i] = *reinterpret_cast<const float4*>(Qp + (size_t)i * ROWSTRIDE);

    for (int w = 0; w < 16; w += 2) {
        P2_WINDOW(w,     0, 1)
        P2_WINDOW(w + 1, 1, 0)
    }

    float* outp = out + ((size_t)n * L_SEQ + l0) * ROWSTRIDE + h * 64 + m0;
#pragma unroll
    for (int i = 0; i < 8; ++i) {
        const float z = 1.0f / zd[i] + EPSV;
        *reinterpret_cast<float4*>(outp + (size_t)i * ROWSTRIDE) =
            make_float4(acc[i][0] * z, acc[i][1] * z, acc[i][2] * z, acc[i][3] * z);
        *reinterpret_cast<float4*>(outp + (size_t)i * ROWSTRIDE + 4) =
            make_float4(acc[i][4] * z, acc[i][5] * z, acc[i][6] * z, acc[i][7] * z);
    }
}

extern "C" void kernel_launch(void* const* d_in, const int* in_sizes, int n_in,
                              void* d_out, int out_size, void* d_ws, size_t ws_size,
                              hipStream_t stream) {
    const float* Q = (const float*)d_in[0];
    const float* K = (const float*)d_in[1];
    const float* V = (const float*)d_in[2];
    float* out = (float*)d_out;
    float* ws  = (float*)d_ws;

    const size_t per_slice = (size_t)SLICE * sizeof(float);   // ~1.06 MB
    const bool split = ws_size >= per_slice * CH_SPLIT;

    if (split) {
        kv_pass_kernel<<<dim3(2, NH_TOT, CH_SPLIT), 64, 0, stream>>>(K, V, ws, 1);
        reduce_kernel<<<SLICE / 256, 256, 0, stream>>>(ws, CH_SPLIT);
    } else {
        hipMemsetAsync(ws, 0, per_slice, stream);
        kv_pass_kernel<<<dim3(2, NH_TOT, CH_SPLIT), 64, 0, stream>>>(K, V, ws, 0);
    }
    out_kernel<<<dim3(64, NH_TOT), 128, 0, stream>>>(Q, ws, out);
}

// Round 5
// 814.101 us; speedup vs baseline: 2.0613x; 2.0613x over previous
//
#include <hip/hip_runtime.h>

// Linear attention (non-causal), N=4, L=8192, H=16, D=M=64, fp32.
//   fm(x) = elu(x)+1
//   KV[n,h,d,m] = sum_s fm(K[n,s,h,d]) * V[n,s,h,m]
//   Ksum[n,h,d] = sum_s fm(K[n,s,h,d])
//   z[n,l,h]    = 1/(fm(Q[n,l,h,:]) . Ksum[n,h,:]) + 1e-10
//   out[n,l,h,m]= z * sum_d fm(Q[n,l,h,d]) * KV[n,h,d,m]
//
// R4 post-mortem: register spill disaster (VGPR cap 64, 2.5GB scratch writes).
// R5: pass1 = 4-wave blocks, wave-private 64x64 KV partial (8x8 patch = 64 VGPR),
// K via 2KB wave-private LDS (2 ds_read_b128 / 64 FMA, broadcast-friendly
// interleaved layout), V direct-from-global (8-way dup dedup'd by coalescer)
// with 4-slot depth-2 register pipeline (static indices). Block combine in LDS.
// Pass2 = R2-verbatim out_kernel (proven).

#define EPSV      1e-10f
#define L_SEQ     8192
#define NH_TOT    64
#define ROWSTRIDE 1024
#define KV_STRIDE 4160
#define SLICE     (NH_TOT * KV_STRIDE)   // 266240 floats per chunk-slice
#define CH_SPLIT  32
#define QSTRIDE   68

__device__ __forceinline__ float fm(float x) {
    return x > 0.0f ? x + 1.0f : __expf(x);
}

// ==================== Pass 1: KV + Ksum partials ====================
// grid (64 nh, 32 chunk), block 256 = 4 waves; wave w owns s-rows
// [chunk*256 + w*64, +64), processed as 8 tiles of 8 rows.
// Lane patch: d0 = (lane>>3)*8, m0 = (lane&7)*8, acc[8][8].
// kbuf layout [wid][half][64][4]: write addr = lane*16B (contiguous,
// conflict-free); read addr = (r*8+dq)*16B (64 lanes in one 128B region,
// 8-lane broadcast, conflict-free).
__global__ __launch_bounds__(256, 3) void kv_pass_kernel(
    const float* __restrict__ K, const float* __restrict__ V,
    float* __restrict__ ws, int mode)
{
    const int t     = threadIdx.x;
    const int nh    = blockIdx.x;
    const int chunk = blockIdx.y;
    const int n = nh >> 4, h = nh & 15;
    const int wid  = t >> 6;
    const int lane = t & 63;

    const int row8 = lane >> 3;        // staging row within 8-row tile; also d-octet
    const int oct  = lane & 7;         // staging col-octet; also m-octet
    const int d0   = row8 << 3;
    const int m0   = oct << 3;

    __shared__ float kbuf[4][2][64][4];   // 8 KB: wave-private fm(K) tiles
    __shared__ float red[4096];           // 16 KB: cross-wave combine
    __shared__ float ksw[4][64];          // 1 KB: per-wave ksum

    float acc[8][8] = {};
    float ks[8] = {};

    const size_t nbase = (size_t)n * (L_SEQ * ROWSTRIDE) + h * 64;
    const int r0 = chunk * 256 + wid * 64;           // wave's first s-row
    const float* Kst = K + nbase + (size_t)(r0 + row8) * ROWSTRIDE + oct * 8;
    const float* Vp  = V + nbase + (size_t)r0 * ROWSTRIDE + m0;

    // prologue: K tile 0 + V rows 0,1
    float4 kr0 = *reinterpret_cast<const float4*>(Kst);
    float4 kr1 = *reinterpret_cast<const float4*>(Kst + 4);
    float4 vbuf[4][2];
    vbuf[0][0] = *reinterpret_cast<const float4*>(Vp);
    vbuf[0][1] = *reinterpret_cast<const float4*>(Vp + 4);
    vbuf[1][0] = *reinterpret_cast<const float4*>(Vp + ROWSTRIDE);
    vbuf[1][1] = *reinterpret_cast<const float4*>(Vp + ROWSTRIDE + 4);

    for (int tile = 0; tile < 8; ++tile) {
        // fm + ksum + stage current K tile (write addr = lane*16B, contiguous)
        float4 kf0, kf1;
        kf0.x = fm(kr0.x); kf0.y = fm(kr0.y); kf0.z = fm(kr0.z); kf0.w = fm(kr0.w);
        kf1.x = fm(kr1.x); kf1.y = fm(kr1.y); kf1.z = fm(kr1.z); kf1.w = fm(kr1.w);
        ks[0] += kf0.x; ks[1] += kf0.y; ks[2] += kf0.z; ks[3] += kf0.w;
        ks[4] += kf1.x; ks[5] += kf1.y; ks[6] += kf1.z; ks[7] += kf1.w;
        *reinterpret_cast<float4*>(kbuf[wid][0][lane]) = kf0;
        *reinterpret_cast<float4*>(kbuf[wid][1][lane]) = kf1;

        // prefetch next K tile (flies under the 512 FMA below)
        if (tile < 7) {
            const float* kp = Kst + (size_t)(tile + 1) * (8 * ROWSTRIDE);
            kr0 = *reinterpret_cast<const float4*>(kp);
            kr1 = *reinterpret_cast<const float4*>(kp + 4);
        }

#pragma unroll
        for (int r = 0; r < 8; ++r) {
            // k-octet from LDS (broadcast, conflict-free)
            const float4 ka = *reinterpret_cast<const float4*>(kbuf[wid][0][r * 8 + row8]);
            const float4 kb = *reinterpret_cast<const float4*>(kbuf[wid][1][r * 8 + row8]);
            // V pipeline: issue row (tile*8+r+2), depth-2; static slot indices
            if (r < 6 || tile < 7) {
                const float* vp = Vp + (size_t)(tile * 8 + r + 2) * ROWSTRIDE;
                vbuf[(r + 2) & 3][0] = *reinterpret_cast<const float4*>(vp);
                vbuf[(r + 2) & 3][1] = *reinterpret_cast<const float4*>(vp + 4);
            }
            const float4 va = vbuf[r & 3][0];
            const float4 vb = vbuf[r & 3][1];
            const float kv[8] = {ka.x, ka.y, ka.z, ka.w, kb.x, kb.y, kb.z, kb.w};
            const float vv[8] = {va.x, va.y, va.z, va.w, vb.x, vb.y, vb.z, vb.w};
#pragma unroll
            for (int p = 0; p < 8; ++p)
#pragma unroll
                for (int q = 0; q < 8; ++q)
                    acc[p][q] += kv[p] * vv[q];
        }
    }

    // ksum: reduce over lanes sharing oct (bits 3..5) -> every lane has full sum
#pragma unroll
    for (int j = 0; j < 8; ++j) {
        ks[j] += __shfl_xor(ks[j], 8);
        ks[j] += __shfl_xor(ks[j], 16);
        ks[j] += __shfl_xor(ks[j], 32);
    }
    if (lane < 8) {          // lane == oct, one lane per col-octet
#pragma unroll
        for (int j = 0; j < 8; ++j) ksw[wid][lane * 8 + j] = ks[j];
    }

    // cross-wave KV combine (sequential, 4 barriers)
    for (int w = 0; w < 4; ++w) {
        if (wid == w) {
#pragma unroll
            for (int i = 0; i < 8; ++i) {
                float* p = &red[(d0 + i) * 64 + m0];
                float4 a0 = make_float4(acc[i][0], acc[i][1], acc[i][2], acc[i][3]);
                float4 a1 = make_float4(acc[i][4], acc[i][5], acc[i][6], acc[i][7]);
                if (w != 0) {
                    const float4 b0 = *reinterpret_cast<const float4*>(p);
                    const float4 b1 = *reinterpret_cast<const float4*>(p + 4);
                    a0.x += b0.x; a0.y += b0.y; a0.z += b0.z; a0.w += b0.w;
                    a1.x += b1.x; a1.y += b1.y; a1.z += b1.z; a1.w += b1.w;
                }
                *reinterpret_cast<float4*>(p)     = a0;
                *reinterpret_cast<float4*>(p + 4) = a1;
            }
        }
        __syncthreads();
    }

    float* dst = ws + (size_t)(mode ? (chunk * NH_TOT + nh) : nh) * KV_STRIDE;
    if (mode) {
#pragma unroll
        for (int i = 0; i < 4; ++i)
            *reinterpret_cast<float4*>(dst + t * 16 + i * 4) =
                *reinterpret_cast<const float4*>(&red[t * 16 + i * 4]);
        if (t < 64)
            dst[4096 + t] = ksw[0][t] + ksw[1][t] + ksw[2][t] + ksw[3][t];
    } else {
#pragma unroll
        for (int i = 0; i < 16; ++i)
            atomicAdd(dst + t * 16 + i, red[t * 16 + i]);
        if (t < 64)
            atomicAdd(dst + 4096 + t, ksw[0][t] + ksw[1][t] + ksw[2][t] + ksw[3][t]);
    }
}

// ==================== Reduce: sum CH slices into slice 0 ====================
__global__ __launch_bounds__(256) void reduce_kernel(float* __restrict__ ws, int CH)
{
    const int idx = blockIdx.x * 256 + threadIdx.x;
    float s = 0.f;
    for (int c = 0; c < CH; ++c) s += ws[(size_t)c * SLICE + idx];
    ws[idx] = s;
}

// ==================== Pass 2: out = z * (fm(Q) @ KV) ====================
// R2-verbatim (proven). grid (128, 64 nh), block 256.
__global__ __launch_bounds__(256) void out_kernel(
    const float* __restrict__ Q, const float* __restrict__ KVg,
    float* __restrict__ out)
{
    const int t      = threadIdx.x;
    const int lchunk = blockIdx.x;
    const int nh     = blockIdx.y;
    const int n = nh >> 4, h = nh & 15;

    __shared__ float Ql[64 * QSTRIDE];
    __shared__ float KVl[4096];
    __shared__ float Ks[64];
    __shared__ float zl[64];

    const float* kvrow = KVg + (size_t)nh * KV_STRIDE;

#pragma unroll
    for (int j = 0; j < 4; ++j) {
        reinterpret_cast<float4*>(KVl)[t + 256 * j] =
            reinterpret_cast<const float4*>(kvrow)[t + 256 * j];
    }
    if (t < 16) {
        reinterpret_cast<float4*>(Ks)[t] =
            reinterpret_cast<const float4*>(kvrow + 4096)[t];
    }
    __syncthreads();

    const int lane16 = t & 15, grp = t >> 4;
    const int dq = lane16 << 2;
    const float4 ks4 = *reinterpret_cast<const float4*>(&Ks[dq]);
    const size_t qbase = ((size_t)n * L_SEQ + lchunk * 64) * ROWSTRIDE + h * 64;
#pragma unroll
    for (int p = 0; p < 4; ++p) {
        const int rr = p * 16 + grp;
        const float4 qg = *reinterpret_cast<const float4*>(Q + qbase + (size_t)rr * ROWSTRIDE + dq);
        float4 qf;
        qf.x = fm(qg.x); qf.y = fm(qg.y); qf.z = fm(qg.z); qf.w = fm(qg.w);
        *reinterpret_cast<float4*>(&Ql[rr * QSTRIDE + dq]) = qf;
        float dp = qf.x * ks4.x + qf.y * ks4.y + qf.z * ks4.z + qf.w * ks4.w;
        dp += __shfl_xor(dp, 1);
        dp += __shfl_xor(dp, 2);
        dp += __shfl_xor(dp, 4);
        dp += __shfl_xor(dp, 8);
        if (lane16 == 0) zl[rr] = 1.0f / dp + EPSV;
    }
    __syncthreads();

    const int r0 = grp << 2;
    const int c0 = lane16 << 2;
    float acc[4][4] = {};
#pragma unroll 2
    for (int d = 0; d < 64; d += 4) {
        const float4 b0 = *reinterpret_cast<const float4*>(&KVl[(d + 0) * 64 + c0]);
        const float4 b1 = *reinterpret_cast<const float4*>(&KVl[(d + 1) * 64 + c0]);
        const float4 b2 = *reinterpret_cast<const float4*>(&KVl[(d + 2) * 64 + c0]);
        const float4 b3 = *reinterpret_cast<const float4*>(&KVl[(d + 3) * 64 + c0]);
#define DO_ROW(i) do {                                                              \
        const float4 q = *reinterpret_cast<const float4*>(&Ql[(r0 + (i)) * QSTRIDE + d]); \
        acc[i][0] += q.x * b0.x + q.y * b1.x + q.z * b2.x + q.w * b3.x;             \
        acc[i][1] += q.x * b0.y + q.y * b1.y + q.z * b2.y + q.w * b3.y;             \
        acc[i][2] += q.x * b0.z + q.y * b1.z + q.z * b2.z + q.w * b3.z;             \
        acc[i][3] += q.x * b0.w + q.y * b1.w + q.z * b2.w + q.w * b3.w;             \
    } while (0)
        DO_ROW(0); DO_ROW(1); DO_ROW(2); DO_ROW(3);
#undef DO_ROW
    }

#pragma unroll
    for (int i = 0; i < 4; ++i) {
        const float z = zl[r0 + i];
        float4 o;
        o.x = acc[i][0] * z; o.y = acc[i][1] * z; o.z = acc[i][2] * z; o.w = acc[i][3] * z;
        *reinterpret_cast<float4*>(out + qbase + (size_t)(r0 + i) * ROWSTRIDE + c0) = o;
    }
}

extern "C" void kernel_launch(void* const* d_in, const int* in_sizes, int n_in,
                              void* d_out, int out_size, void* d_ws, size_t ws_size,
                              hipStream_t stream) {
    const float* Q = (const float*)d_in[0];
    const float* K = (const float*)d_in[1];
    const float* V = (const float*)d_in[2];
    float* out = (float*)d_out;
    float* ws  = (float*)d_ws;

    const size_t per_slice = (size_t)SLICE * sizeof(float);   // ~1.06 MB
    const bool split = ws_size >= per_slice * CH_SPLIT;

    if (split) {
        kv_pass_kernel<<<dim3(NH_TOT, CH_SPLIT), 256, 0, stream>>>(K, V, ws, 1);
        reduce_kernel<<<SLICE / 256, 256, 0, stream>>>(ws, CH_SPLIT);
    } else {
        hipMemsetAsync(ws, 0, per_slice, stream);
        kv_pass_kernel<<<dim3(NH_TOT, CH_SPLIT), 256, 0, stream>>>(K, V, ws, 0);
    }
    out_kernel<<<dim3(L_SEQ / 64, NH_TOT), 256, 0, stream>>>(Q, ws, out);
}

// Round 6
// 553.485 us; speedup vs baseline: 3.0319x; 1.4709x over previous
//
#include <hip/hip_runtime.h>

// Linear attention (non-causal), N=4, L=8192, H=16, D=M=64, fp32.
//   fm(x) = elu(x)+1
//   KV[n,h,d,m] = sum_s fm(K[n,s,h,d]) * V[n,s,h,m]   (stored as [d][m])
//   Ksum[n,h,d] = sum_s fm(K[n,s,h,d])
//   z[n,l,h]    = 1/(fm(Q[n,l,h,:]) . Ksum[n,h,:]) + 1e-10
//   out[n,l,h,m]= z * sum_d fm(Q[n,l,h,d]) * KV[d][m]
//
// R5 post-mortem: compiler targeted LDS-implied occupancy (6 blk/CU @25.6KB
// -> 84 VGPR cap) and spilled acc. R6: align LDS (34KB -> 4 blk/CU) with
// __launch_bounds__(256,4) (cap 128); 8x8 patch/lane, wave-private K AND V
// LDS windows (oct-major stride-68 layout, conflict-free both sides),
// tile-level prefetch only (16 regs). DS model: 4.5 instr/row = 54 cyc/row/CU
// vs 128 VALU -> pass1 ~50us. Pass2/reduce unchanged (proven).

#define EPSV      1e-10f
#define L_SEQ     8192
#define NH_TOT    64
#define ROWSTRIDE 1024
#define KV_STRIDE 4160
#define SLICE     (NH_TOT * KV_STRIDE)   // 266240 floats per chunk-slice
#define CH_SPLIT  32
#define QSTRIDE   68
#define WSTRIDE   68                     // LDS oct stride (floats): 4*68B step -> conflict-free

__device__ __forceinline__ float fm(float x) {
    return x > 0.0f ? x + 1.0f : __expf(x);
}

// ==================== Pass 1: KV + Ksum partials ====================
// grid (64 nh, 32 chunk), block 256 = 4 waves; wave w owns s-rows
// [chunk*256 + w*64, +64), processed as 8 tiles of 8 rows.
// Lane patch: d0=(lane>>3)*8, m0=(lane&7)*8, acc[8][8] (64 VGPR).
// LDS windows per wave: K/V [oct][row][8] with oct stride 68 floats:
//   write (lane: oct=l&7,row=l>>3) starts at bank 4*(l&7)+8*(l>>3) -> 8
//   4-bank clusters x 8 lanes = minimum phases; read (lane group l>>3 or l&7)
//   starts 4*g + 8*r -> 8 clusters, 8-lane same-address broadcast. Conflict-free.
__global__ __launch_bounds__(256, 4) void kv_pass_kernel(
    const float* __restrict__ K, const float* __restrict__ V,
    float* __restrict__ ws, int mode)
{
    const int t     = threadIdx.x;
    const int nh    = blockIdx.x;
    const int chunk = blockIdx.y;
    const int n = nh >> 4, h = nh & 15;
    const int wid  = t >> 6;
    const int lane = t & 63;

    const int row8 = lane >> 3;        // staging row in tile; also d-octet idx
    const int oct  = lane & 7;         // staging col-octet; also m-octet idx
    const int d0   = row8 << 3;
    const int m0   = oct << 3;

    __shared__ float kws[4][8 * WSTRIDE];   // 8.5 KB: wave-private fm(K) tiles
    __shared__ float vws[4][8 * WSTRIDE];   // 8.5 KB: wave-private V tiles
    __shared__ float red[4096];             // 16 KB: cross-wave combine
    __shared__ float ksw[4][64];            // 1 KB: per-wave ksum

    float acc[8][8] = {};
    float ks[8] = {};

    const size_t nbase = (size_t)n * (L_SEQ * ROWSTRIDE) + h * 64;
    const int r0 = chunk * 256 + wid * 64;           // wave's first s-row
    const float* Kst = K + nbase + (size_t)(r0 + row8) * ROWSTRIDE + oct * 8;
    const float* Vst = V + nbase + (size_t)(r0 + row8) * ROWSTRIDE + oct * 8;

    // write offset (floats): oct-major
    const int wofs = oct * WSTRIDE + row8 * 8;
    // read base offsets
    const int krd = row8 * WSTRIDE;    // lane's d-octet group
    const int vrd = oct * WSTRIDE;     // lane's m-octet group

    // prologue: prefetch tile 0
    float4 kr0 = *reinterpret_cast<const float4*>(Kst);
    float4 kr1 = *reinterpret_cast<const float4*>(Kst + 4);
    float4 vr0 = *reinterpret_cast<const float4*>(Vst);
    float4 vr1 = *reinterpret_cast<const float4*>(Vst + 4);

    for (int tile = 0; tile < 8; ++tile) {
        // fm + ksum + stage current tile into wave-private LDS
        float4 kf0, kf1;
        kf0.x = fm(kr0.x); kf0.y = fm(kr0.y); kf0.z = fm(kr0.z); kf0.w = fm(kr0.w);
        kf1.x = fm(kr1.x); kf1.y = fm(kr1.y); kf1.z = fm(kr1.z); kf1.w = fm(kr1.w);
        ks[0] += kf0.x; ks[1] += kf0.y; ks[2] += kf0.z; ks[3] += kf0.w;
        ks[4] += kf1.x; ks[5] += kf1.y; ks[6] += kf1.z; ks[7] += kf1.w;
        *reinterpret_cast<float4*>(&kws[wid][wofs])     = kf0;
        *reinterpret_cast<float4*>(&kws[wid][wofs + 4]) = kf1;
        *reinterpret_cast<float4*>(&vws[wid][wofs])     = vr0;
        *reinterpret_cast<float4*>(&vws[wid][wofs + 4]) = vr1;

        // prefetch next tile (flies under the 512 FMA below)
        if (tile < 7) {
            const float* kp = Kst + (size_t)(tile + 1) * (8 * ROWSTRIDE);
            const float* vp = Vst + (size_t)(tile + 1) * (8 * ROWSTRIDE);
            kr0 = *reinterpret_cast<const float4*>(kp);
            kr1 = *reinterpret_cast<const float4*>(kp + 4);
            vr0 = *reinterpret_cast<const float4*>(vp);
            vr1 = *reinterpret_cast<const float4*>(vp + 4);
        }

#pragma unroll
        for (int r = 0; r < 8; ++r) {
            const float4 ka = *reinterpret_cast<const float4*>(&kws[wid][krd + r * 8]);
            const float4 kb = *reinterpret_cast<const float4*>(&kws[wid][krd + r * 8 + 4]);
            const float4 va = *reinterpret_cast<const float4*>(&vws[wid][vrd + r * 8]);
            const float4 vb = *reinterpret_cast<const float4*>(&vws[wid][vrd + r * 8 + 4]);
            const float kv[8] = {ka.x, ka.y, ka.z, ka.w, kb.x, kb.y, kb.z, kb.w};
            const float vv[8] = {va.x, va.y, va.z, va.w, vb.x, vb.y, vb.z, vb.w};
#pragma unroll
            for (int p = 0; p < 8; ++p)
#pragma unroll
                for (int q = 0; q < 8; ++q)
                    acc[p][q] += kv[p] * vv[q];
        }
    }

    // ksum: reduce over lanes sharing oct (bits 3..5)
#pragma unroll
    for (int j = 0; j < 8; ++j) {
        ks[j] += __shfl_xor(ks[j], 8);
        ks[j] += __shfl_xor(ks[j], 16);
        ks[j] += __shfl_xor(ks[j], 32);
    }
    if (lane < 8) {          // lane == oct, one lane per col-octet
#pragma unroll
        for (int j = 0; j < 8; ++j) ksw[wid][lane * 8 + j] = ks[j];
    }

    // cross-wave KV combine (sequential, 4 barriers)
    for (int w = 0; w < 4; ++w) {
        if (wid == w) {
#pragma unroll
            for (int i = 0; i < 8; ++i) {
                float* p = &red[(d0 + i) * 64 + m0];
                float4 a0 = make_float4(acc[i][0], acc[i][1], acc[i][2], acc[i][3]);
                float4 a1 = make_float4(acc[i][4], acc[i][5], acc[i][6], acc[i][7]);
                if (w != 0) {
                    const float4 b0 = *reinterpret_cast<const float4*>(p);
                    const float4 b1 = *reinterpret_cast<const float4*>(p + 4);
                    a0.x += b0.x; a0.y += b0.y; a0.z += b0.z; a0.w += b0.w;
                    a1.x += b1.x; a1.y += b1.y; a1.z += b1.z; a1.w += b1.w;
                }
                *reinterpret_cast<float4*>(p)     = a0;
                *reinterpret_cast<float4*>(p + 4) = a1;
            }
        }
        __syncthreads();
    }

    float* dst = ws + (size_t)(mode ? (chunk * NH_TOT + nh) : nh) * KV_STRIDE;
    if (mode) {
#pragma unroll
        for (int i = 0; i < 4; ++i)
            *reinterpret_cast<float4*>(dst + t * 16 + i * 4) =
                *reinterpret_cast<const float4*>(&red[t * 16 + i * 4]);
        if (t < 64)
            dst[4096 + t] = ksw[0][t] + ksw[1][t] + ksw[2][t] + ksw[3][t];
    } else {
#pragma unroll
        for (int i = 0; i < 16; ++i)
            atomicAdd(dst + t * 16 + i, red[t * 16 + i]);
        if (t < 64)
            atomicAdd(dst + 4096 + t, ksw[0][t] + ksw[1][t] + ksw[2][t] + ksw[3][t]);
    }
}

// ==================== Reduce: sum CH slices into slice 0 ====================
__global__ __launch_bounds__(256) void reduce_kernel(float* __restrict__ ws, int CH)
{
    const int idx = blockIdx.x * 256 + threadIdx.x;
    float s = 0.f;
    for (int c = 0; c < CH; ++c) s += ws[(size_t)c * SLICE + idx];
    ws[idx] = s;
}

// ==================== Pass 2: out = z * (fm(Q) @ KV) ====================
// R2-verbatim (proven). grid (128, 64 nh), block 256.
__global__ __launch_bounds__(256) void out_kernel(
    const float* __restrict__ Q, const float* __restrict__ KVg,
    float* __restrict__ out)
{
    const int t      = threadIdx.x;
    const int lchunk = blockIdx.x;
    const int nh     = blockIdx.y;
    const int n = nh >> 4, h = nh & 15;

    __shared__ float Ql[64 * QSTRIDE];
    __shared__ float KVl[4096];
    __shared__ float Ks[64];
    __shared__ float zl[64];

    const float* kvrow = KVg + (size_t)nh * KV_STRIDE;

#pragma unroll
    for (int j = 0; j < 4; ++j) {
        reinterpret_cast<float4*>(KVl)[t + 256 * j] =
            reinterpret_cast<const float4*>(kvrow)[t + 256 * j];
    }
    if (t < 16) {
        reinterpret_cast<float4*>(Ks)[t] =
            reinterpret_cast<const float4*>(kvrow + 4096)[t];
    }
    __syncthreads();

    const int lane16 = t & 15, grp = t >> 4;
    const int dq = lane16 << 2;
    const float4 ks4 = *reinterpret_cast<const float4*>(&Ks[dq]);
    const size_t qbase = ((size_t)n * L_SEQ + lchunk * 64) * ROWSTRIDE + h * 64;
#pragma unroll
    for (int p = 0; p < 4; ++p) {
        const int rr = p * 16 + grp;
        const float4 qg = *reinterpret_cast<const float4*>(Q + qbase + (size_t)rr * ROWSTRIDE + dq);
        float4 qf;
        qf.x = fm(qg.x); qf.y = fm(qg.y); qf.z = fm(qg.z); qf.w = fm(qg.w);
        *reinterpret_cast<float4*>(&Ql[rr * QSTRIDE + dq]) = qf;
        float dp = qf.x * ks4.x + qf.y * ks4.y + qf.z * ks4.z + qf.w * ks4.w;
        dp += __shfl_xor(dp, 1);
        dp += __shfl_xor(dp, 2);
        dp += __shfl_xor(dp, 4);
        dp += __shfl_xor(dp, 8);
        if (lane16 == 0) zl[rr] = 1.0f / dp + EPSV;
    }
    __syncthreads();

    const int r0 = grp << 2;
    const int c0 = lane16 << 2;
    float acc[4][4] = {};
#pragma unroll 2
    for (int d = 0; d < 64; d += 4) {
        const float4 b0 = *reinterpret_cast<const float4*>(&KVl[(d + 0) * 64 + c0]);
        const float4 b1 = *reinterpret_cast<const float4*>(&KVl[(d + 1) * 64 + c0]);
        const float4 b2 = *reinterpret_cast<const float4*>(&KVl[(d + 2) * 64 + c0]);
        const float4 b3 = *reinterpret_cast<const float4*>(&KVl[(d + 3) * 64 + c0]);
#define DO_ROW(i) do {                                                              \
        const float4 q = *reinterpret_cast<const float4*>(&Ql[(r0 + (i)) * QSTRIDE + d]); \
        acc[i][0] += q.x * b0.x + q.y * b1.x + q.z * b2.x + q.w * b3.x;             \
        acc[i][1] += q.x * b0.y + q.y * b1.y + q.z * b2.y + q.w * b3.y;             \
        acc[i][2] += q.x * b0.z + q.y * b1.z + q.z * b2.z + q.w * b3.z;             \
        acc[i][3] += q.x * b0.w + q.y * b1.w + q.z * b2.w + q.w * b3.w;             \
    } while (0)
        DO_ROW(0); DO_ROW(1); DO_ROW(2); DO_ROW(3);
#undef DO_ROW
    }

#pragma unroll
    for (int i = 0; i < 4; ++i) {
        const float z = zl[r0 + i];
        float4 o;
        o.x = acc[i][0] * z; o.y = acc[i][1] * z; o.z = acc[i][2] * z; o.w = acc[i][3] * z;
        *reinterpret_cast<float4*>(out + qbase + (size_t)(r0 + i) * ROWSTRIDE + c0) = o;
    }
}

extern "C" void kernel_launch(void* const* d_in, const int* in_sizes, int n_in,
                              void* d_out, int out_size, void* d_ws, size_t ws_size,
                              hipStream_t stream) {
    const float* Q = (const float*)d_in[0];
    const float* K = (const float*)d_in[1];
    const float* V = (const float*)d_in[2];
    float* out = (float*)d_out;
    float* ws  = (float*)d_ws;

    const size_t per_slice = (size_t)SLICE * sizeof(float);   // ~1.06 MB
    const bool split = ws_size >= per_slice * CH_SPLIT;

    if (split) {
        kv_pass_kernel<<<dim3(NH_TOT, CH_SPLIT), 256, 0, stream>>>(K, V, ws, 1);
        reduce_kernel<<<SLICE / 256, 256, 0, stream>>>(ws, CH_SPLIT);
    } else {
        hipMemsetAsync(ws, 0, per_slice, stream);
        kv_pass_kernel<<<dim3(NH_TOT, CH_SPLIT), 256, 0, stream>>>(K, V, ws, 0);
    }
    out_kernel<<<dim3(L_SEQ / 64, NH_TOT), 256, 0, stream>>>(Q, ws, out);
}

// Round 7
// 530.751 us; speedup vs baseline: 3.1617x; 1.0428x over previous
//
#include <hip/hip_runtime.h>

// Linear attention (non-causal), N=4, L=8192, H=16, D=M=64, fp32.
//   fm(x) = elu(x)+1
//   KV[n,h,d,m] = sum_s fm(K[n,s,h,d]) * V[n,s,h,m]   (stored as [d][m])
//   Ksum[n,h,d] = sum_s fm(K[n,s,h,d])
//   z[n,l,h]    = 1/(fm(Q[n,l,h,:]) . Ksum[n,h,:]) + 1e-10
//   out[n,l,h,m]= z * sum_d fm(Q[n,l,h,d]) * KV[d][m]
//
// R6 post-mortem: launch_bounds(256,4) is only a MINIMUM — LLVM's occupancy
// heuristic targeted 8 waves/EU (64 VGPR) and spilled acc (FETCH 622MB).
// R7: amdgpu_waves_per_eu(4,4) pins the budget at 128 VGPR; combine buffer
// aliased onto the wave windows (LDS 34.8->17.4KB) with an explicit barrier;
// tile loop unroll-pinned. Structure otherwise identical to R6.

#define EPSV      1e-10f
#define L_SEQ     8192
#define NH_TOT    64
#define ROWSTRIDE 1024
#define KV_STRIDE 4160
#define SLICE     (NH_TOT * KV_STRIDE)   // 266240 floats per chunk-slice
#define CH_SPLIT  32
#define QSTRIDE   68
#define WSTRIDE   68                     // LDS oct stride (floats)
#define WAVEWIN   (2 * 8 * WSTRIDE)      // K+V window floats per wave (1088)

__device__ __forceinline__ float fm(float x) {
    return x > 0.0f ? x + 1.0f : __expf(x);
}

// ==================== Pass 1: KV + Ksum partials ====================
// grid (64 nh, 32 chunk), block 256 = 4 waves; wave w owns s-rows
// [chunk*256 + w*64, +64), processed as 8 tiles of 8 rows.
// Lane patch: d0=(lane>>3)*8, m0=(lane&7)*8, acc[8][8] (64 VGPR).
// Wave-private LDS windows [oct][row][8], oct stride 68 floats:
// reads are 8-lane same-address broadcasts across conflict-free clusters;
// writes are ~4-way (measured 1.85M cyc total ~ 3us — acceptable).
__global__ __launch_bounds__(256) __attribute__((amdgpu_waves_per_eu(4, 4)))
void kv_pass_kernel(
    const float* __restrict__ K, const float* __restrict__ V,
    float* __restrict__ ws, int mode)
{
    const int t     = threadIdx.x;
    const int nh    = blockIdx.x;
    const int chunk = blockIdx.y;
    const int n = nh >> 4, h = nh & 15;
    const int wid  = t >> 6;
    const int lane = t & 63;

    const int row8 = lane >> 3;        // staging row in tile; also d-octet idx
    const int oct  = lane & 7;         // staging col-octet; also m-octet idx
    const int d0   = row8 << 3;
    const int m0   = oct << 3;

    __shared__ float smem[4 * WAVEWIN];   // 17 KB: wave windows, then combine buf
    __shared__ float ksw[4][64];          // 1 KB: per-wave ksum

    float* kws = &smem[wid * WAVEWIN];            // this wave's fm(K) window
    float* vws = kws + 8 * WSTRIDE;               // this wave's V window

    float acc[8][8] = {};
    float ks[8] = {};

    const size_t nbase = (size_t)n * (L_SEQ * ROWSTRIDE) + h * 64;
    const int r0 = chunk * 256 + wid * 64;           // wave's first s-row
    const float* Kst = K + nbase + (size_t)(r0 + row8) * ROWSTRIDE + oct * 8;
    const float* Vst = V + nbase + (size_t)(r0 + row8) * ROWSTRIDE + oct * 8;

    const int wofs = oct * WSTRIDE + row8 * 8;   // write offset (floats)
    const int krd  = row8 * WSTRIDE;             // K read base (lane's d-octet)
    const int vrd  = oct * WSTRIDE;              // V read base (lane's m-octet)

    // prologue: prefetch tile 0
    float4 kr0 = *reinterpret_cast<const float4*>(Kst);
    float4 kr1 = *reinterpret_cast<const float4*>(Kst + 4);
    float4 vr0 = *reinterpret_cast<const float4*>(Vst);
    float4 vr1 = *reinterpret_cast<const float4*>(Vst + 4);

#pragma unroll 1
    for (int tile = 0; tile < 8; ++tile) {
        // fm + ksum + stage current tile into wave-private LDS
        float4 kf0, kf1;
        kf0.x = fm(kr0.x); kf0.y = fm(kr0.y); kf0.z = fm(kr0.z); kf0.w = fm(kr0.w);
        kf1.x = fm(kr1.x); kf1.y = fm(kr1.y); kf1.z = fm(kr1.z); kf1.w = fm(kr1.w);
        ks[0] += kf0.x; ks[1] += kf0.y; ks[2] += kf0.z; ks[3] += kf0.w;
        ks[4] += kf1.x; ks[5] += kf1.y; ks[6] += kf1.z; ks[7] += kf1.w;
        *reinterpret_cast<float4*>(&kws[wofs])     = kf0;
        *reinterpret_cast<float4*>(&kws[wofs + 4]) = kf1;
        *reinterpret_cast<float4*>(&vws[wofs])     = vr0;
        *reinterpret_cast<float4*>(&vws[wofs + 4]) = vr1;

        // prefetch next tile (flies under the 512 FMA below)
        if (tile < 7) {
            const float* kp = Kst + (size_t)(tile + 1) * (8 * ROWSTRIDE);
            const float* vp = Vst + (size_t)(tile + 1) * (8 * ROWSTRIDE);
            kr0 = *reinterpret_cast<const float4*>(kp);
            kr1 = *reinterpret_cast<const float4*>(kp + 4);
            vr0 = *reinterpret_cast<const float4*>(vp);
            vr1 = *reinterpret_cast<const float4*>(vp + 4);
        }

#pragma unroll
        for (int r = 0; r < 8; ++r) {
            const float4 ka = *reinterpret_cast<const float4*>(&kws[krd + r * 8]);
            const float4 kb = *reinterpret_cast<const float4*>(&kws[krd + r * 8 + 4]);
            const float4 va = *reinterpret_cast<const float4*>(&vws[vrd + r * 8]);
            const float4 vb = *reinterpret_cast<const float4*>(&vws[vrd + r * 8 + 4]);
            const float kv[8] = {ka.x, ka.y, ka.z, ka.w, kb.x, kb.y, kb.z, kb.w};
            const float vv[8] = {va.x, va.y, va.z, va.w, vb.x, vb.y, vb.z, vb.w};
#pragma unroll
            for (int p = 0; p < 8; ++p)
#pragma unroll
                for (int q = 0; q < 8; ++q)
                    acc[p][q] += kv[p] * vv[q];
        }
    }

    // ksum: reduce over lanes sharing oct (bits 3..5)
#pragma unroll
    for (int j = 0; j < 8; ++j) {
        ks[j] += __shfl_xor(ks[j], 8);
        ks[j] += __shfl_xor(ks[j], 16);
        ks[j] += __shfl_xor(ks[j], 32);
    }
    if (lane < 8) {          // lane == oct, one lane per col-octet
#pragma unroll
        for (int j = 0; j < 8; ++j) ksw[wid][lane * 8 + j] = ks[j];
    }

    // all waves done with their windows before we alias them as the combine buf
    __syncthreads();
    float* red = smem;   // 4096 floats needed, 4352 available

    // cross-wave KV combine (sequential, 4 barriers)
    for (int w = 0; w < 4; ++w) {
        if (wid == w) {
#pragma unroll
            for (int i = 0; i < 8; ++i) {
                float* p = &red[(d0 + i) * 64 + m0];
                float4 a0 = make_float4(acc[i][0], acc[i][1], acc[i][2], acc[i][3]);
                float4 a1 = make_float4(acc[i][4], acc[i][5], acc[i][6], acc[i][7]);
                if (w != 0) {
                    const float4 b0 = *reinterpret_cast<const float4*>(p);
                    const float4 b1 = *reinterpret_cast<const float4*>(p + 4);
                    a0.x += b0.x; a0.y += b0.y; a0.z += b0.z; a0.w += b0.w;
                    a1.x += b1.x; a1.y += b1.y; a1.z += b1.z; a1.w += b1.w;
                }
                *reinterpret_cast<float4*>(p)     = a0;
                *reinterpret_cast<float4*>(p + 4) = a1;
            }
        }
        __syncthreads();
    }

    float* dst = ws + (size_t)(mode ? (chunk * NH_TOT + nh) : nh) * KV_STRIDE;
    if (mode) {
#pragma unroll
        for (int i = 0; i < 4; ++i)
            *reinterpret_cast<float4*>(dst + t * 16 + i * 4) =
                *reinterpret_cast<const float4*>(&red[t * 16 + i * 4]);
        if (t < 64)
            dst[4096 + t] = ksw[0][t] + ksw[1][t] + ksw[2][t] + ksw[3][t];
    } else {
#pragma unroll
        for (int i = 0; i < 16; ++i)
            atomicAdd(dst + t * 16 + i, red[t * 16 + i]);
        if (t < 64)
            atomicAdd(dst + 4096 + t, ksw[0][t] + ksw[1][t] + ksw[2][t] + ksw[3][t]);
    }
}

// ==================== Reduce: sum CH slices into slice 0 ====================
__global__ __launch_bounds__(256) void reduce_kernel(float* __restrict__ ws, int CH)
{
    const int idx = blockIdx.x * 256 + threadIdx.x;
    float s = 0.f;
    for (int c = 0; c < CH; ++c) s += ws[(size_t)c * SLICE + idx];
    ws[idx] = s;
}

// ==================== Pass 2: out = z * (fm(Q) @ KV) ====================
// R2-verbatim (proven). grid (128, 64 nh), block 256.
__global__ __launch_bounds__(256) void out_kernel(
    const float* __restrict__ Q, const float* __restrict__ KVg,
    float* __restrict__ out)
{
    const int t      = threadIdx.x;
    const int lchunk = blockIdx.x;
    const int nh     = blockIdx.y;
    const int n = nh >> 4, h = nh & 15;

    __shared__ float Ql[64 * QSTRIDE];
    __shared__ float KVl[4096];
    __shared__ float Ks[64];
    __shared__ float zl[64];

    const float* kvrow = KVg + (size_t)nh * KV_STRIDE;

#pragma unroll
    for (int j = 0; j < 4; ++j) {
        reinterpret_cast<float4*>(KVl)[t + 256 * j] =
            reinterpret_cast<const float4*>(kvrow)[t + 256 * j];
    }
    if (t < 16) {
        reinterpret_cast<float4*>(Ks)[t] =
            reinterpret_cast<const float4*>(kvrow + 4096)[t];
    }
    __syncthreads();

    const int lane16 = t & 15, grp = t >> 4;
    const int dq = lane16 << 2;
    const float4 ks4 = *reinterpret_cast<const float4*>(&Ks[dq]);
    const size_t qbase = ((size_t)n * L_SEQ + lchunk * 64) * ROWSTRIDE + h * 64;
#pragma unroll
    for (int p = 0; p < 4; ++p) {
        const int rr = p * 16 + grp;
        const float4 qg = *reinterpret_cast<const float4*>(Q + qbase + (size_t)rr * ROWSTRIDE + dq);
        float4 qf;
        qf.x = fm(qg.x); qf.y = fm(qg.y); qf.z = fm(qg.z); qf.w = fm(qg.w);
        *reinterpret_cast<float4*>(&Ql[rr * QSTRIDE + dq]) = qf;
        float dp = qf.x * ks4.x + qf.y * ks4.y + qf.z * ks4.z + qf.w * ks4.w;
        dp += __shfl_xor(dp, 1);
        dp += __shfl_xor(dp, 2);
        dp += __shfl_xor(dp, 4);
        dp += __shfl_xor(dp, 8);
        if (lane16 == 0) zl[rr] = 1.0f / dp + EPSV;
    }
    __syncthreads();

    const int r0 = grp << 2;
    const int c0 = lane16 << 2;
    float acc[4][4] = {};
#pragma unroll 2
    for (int d = 0; d < 64; d += 4) {
        const float4 b0 = *reinterpret_cast<const float4*>(&KVl[(d + 0) * 64 + c0]);
        const float4 b1 = *reinterpret_cast<const float4*>(&KVl[(d + 1) * 64 + c0]);
        const float4 b2 = *reinterpret_cast<const float4*>(&KVl[(d + 2) * 64 + c0]);
        const float4 b3 = *reinterpret_cast<const float4*>(&KVl[(d + 3) * 64 + c0]);
#define DO_ROW(i) do {                                                              \
        const float4 q = *reinterpret_cast<const float4*>(&Ql[(r0 + (i)) * QSTRIDE + d]); \
        acc[i][0] += q.x * b0.x + q.y * b1.x + q.z * b2.x + q.w * b3.x;             \
        acc[i][1] += q.x * b0.y + q.y * b1.y + q.z * b2.y + q.w * b3.y;             \
        acc[i][2] += q.x * b0.z + q.y * b1.z + q.z * b2.z + q.w * b3.z;             \
        acc[i][3] += q.x * b0.w + q.y * b1.w + q.z * b2.w + q.w * b3.w;             \
    } while (0)
        DO_ROW(0); DO_ROW(1); DO_ROW(2); DO_ROW(3);
#undef DO_ROW
    }

#pragma unroll
    for (int i = 0; i < 4; ++i) {
        const float z = zl[r0 + i];
        float4 o;
        o.x = acc[i][0] * z; o.y = acc[i][1] * z; o.z = acc[i][2] * z; o.w = acc[i][3] * z;
        *reinterpret_cast<float4*>(out + qbase + (size_t)(r0 + i) * ROWSTRIDE + c0) = o;
    }
}

extern "C" void kernel_launch(void* const* d_in, const int* in_sizes, int n_in,
                              void* d_out, int out_size, void* d_ws, size_t ws_size,
                              hipStream_t stream) {
    const float* Q = (const float*)d_in[0];
    const float* K = (const float*)d_in[1];
    const float* V = (const float*)d_in[2];
    float* out = (float*)d_out;
    float* ws  = (float*)d_ws;

    const size_t per_slice = (size_t)SLICE * sizeof(float);   // ~1.06 MB
    const bool split = ws_size >= per_slice * CH_SPLIT;

    if (split) {
        kv_pass_kernel<<<dim3(NH_TOT, CH_SPLIT), 256, 0, stream>>>(K, V, ws, 1);
        reduce_kernel<<<SLICE / 256, 256, 0, stream>>>(ws, CH_SPLIT);
    } else {
        hipMemsetAsync(ws, 0, per_slice, stream);
        kv_pass_kernel<<<dim3(NH_TOT, CH_SPLIT), 256, 0, stream>>>(K, V, ws, 0);
    }
    out_kernel<<<dim3(L_SEQ / 64, NH_TOT), 256, 0, stream>>>(Q, ws, out);
}

// Round 8
// 191.511 us; speedup vs baseline: 8.7623x; 2.7714x over previous
//
#include <hip/hip_runtime.h>

// Linear attention (non-causal), N=4, L=8192, H=16, D=M=64, fp32.
//   fm(x) = elu(x)+1
//   KV[n,h,d,m] = sum_s fm(K[n,s,h,d]) * V[n,s,h,m]   (stored as [d][m])
//   Ksum[n,h,d] = sum_s fm(K[n,s,h,d])
//   z[n,l,h]    = 1/(fm(Q[n,l,h,:]) . Ksum[n,h,:]) + 1e-10
//   out[n,l,h,m]= z * sum_d fm(Q[n,l,h,d]) * KV[d][m]
//
// R7 post-mortem: VGPR budget = 512 / backend-min-waves-per-EU, and HIP's
// launch_bounds 2nd arg appears to set min = 2x its value (R5: 3->85=512/6,
// R6: 4->64=512/8). R8: launch_bounds(256,2) -> min 4 waves/EU -> budget 128
// >= demand (~116). Kernel body R6-verbatim otherwise.

#define EPSV      1e-10f
#define L_SEQ     8192
#define NH_TOT    64
#define ROWSTRIDE 1024
#define KV_STRIDE 4160
#define SLICE     (NH_TOT * KV_STRIDE)   // 266240 floats per chunk-slice
#define CH_SPLIT  32
#define QSTRIDE   68
#define WSTRIDE   68                     // LDS oct stride (floats)

__device__ __forceinline__ float fm(float x) {
    return x > 0.0f ? x + 1.0f : __expf(x);
}

// ==================== Pass 1: KV + Ksum partials ====================
// grid (64 nh, 32 chunk), block 256 = 4 waves; wave w owns s-rows
// [chunk*256 + w*64, +64), processed as 8 tiles of 8 rows.
// Lane patch: d0=(lane>>3)*8, m0=(lane&7)*8, acc[8][8] (64 VGPR).
// Wave-private LDS windows [oct][row][8], oct stride 68 floats.
__global__ __launch_bounds__(256, 2) void kv_pass_kernel(
    const float* __restrict__ K, const float* __restrict__ V,
    float* __restrict__ ws, int mode)
{
    const int t     = threadIdx.x;
    const int nh    = blockIdx.x;
    const int chunk = blockIdx.y;
    const int n = nh >> 4, h = nh & 15;
    const int wid  = t >> 6;
    const int lane = t & 63;

    const int row8 = lane >> 3;        // staging row in tile; also d-octet idx
    const int oct  = lane & 7;         // staging col-octet; also m-octet idx
    const int d0   = row8 << 3;
    const int m0   = oct << 3;

    __shared__ float kws[4][8 * WSTRIDE];   // 8.5 KB: wave-private fm(K) tiles
    __shared__ float vws[4][8 * WSTRIDE];   // 8.5 KB: wave-private V tiles
    __shared__ float red[4096];             // 16 KB: cross-wave combine
    __shared__ float ksw[4][64];            // 1 KB: per-wave ksum

    float acc[8][8] = {};
    float ks[8] = {};

    const size_t nbase = (size_t)n * (L_SEQ * ROWSTRIDE) + h * 64;
    const int r0 = chunk * 256 + wid * 64;           // wave's first s-row
    const float* Kst = K + nbase + (size_t)(r0 + row8) * ROWSTRIDE + oct * 8;
    const float* Vst = V + nbase + (size_t)(r0 + row8) * ROWSTRIDE + oct * 8;

    const int wofs = oct * WSTRIDE + row8 * 8;   // write offset (floats)
    const int krd  = row8 * WSTRIDE;             // K read base (lane's d-octet)
    const int vrd  = oct * WSTRIDE;              // V read base (lane's m-octet)

    // prologue: prefetch tile 0
    float4 kr0 = *reinterpret_cast<const float4*>(Kst);
    float4 kr1 = *reinterpret_cast<const float4*>(Kst + 4);
    float4 vr0 = *reinterpret_cast<const float4*>(Vst);
    float4 vr1 = *reinterpret_cast<const float4*>(Vst + 4);

#pragma unroll 1
    for (int tile = 0; tile < 8; ++tile) {
        // fm + ksum + stage current tile into wave-private LDS
        float4 kf0, kf1;
        kf0.x = fm(kr0.x); kf0.y = fm(kr0.y); kf0.z = fm(kr0.z); kf0.w = fm(kr0.w);
        kf1.x = fm(kr1.x); kf1.y = fm(kr1.y); kf1.z = fm(kr1.z); kf1.w = fm(kr1.w);
        ks[0] += kf0.x; ks[1] += kf0.y; ks[2] += kf0.z; ks[3] += kf0.w;
        ks[4] += kf1.x; ks[5] += kf1.y; ks[6] += kf1.z; ks[7] += kf1.w;
        *reinterpret_cast<float4*>(&kws[wid][wofs])     = kf0;
        *reinterpret_cast<float4*>(&kws[wid][wofs + 4]) = kf1;
        *reinterpret_cast<float4*>(&vws[wid][wofs])     = vr0;
        *reinterpret_cast<float4*>(&vws[wid][wofs + 4]) = vr1;

        // prefetch next tile (flies under the 512 FMA below)
        if (tile < 7) {
            const float* kp = Kst + (size_t)(tile + 1) * (8 * ROWSTRIDE);
            const float* vp = Vst + (size_t)(tile + 1) * (8 * ROWSTRIDE);
            kr0 = *reinterpret_cast<const float4*>(kp);
            kr1 = *reinterpret_cast<const float4*>(kp + 4);
            vr0 = *reinterpret_cast<const float4*>(vp);
            vr1 = *reinterpret_cast<const float4*>(vp + 4);
        }

#pragma unroll
        for (int r = 0; r < 8; ++r) {
            const float4 ka = *reinterpret_cast<const float4*>(&kws[wid][krd + r * 8]);
            const float4 kb = *reinterpret_cast<const float4*>(&kws[wid][krd + r * 8 + 4]);
            const float4 va = *reinterpret_cast<const float4*>(&vws[wid][vrd + r * 8]);
            const float4 vb = *reinterpret_cast<const float4*>(&vws[wid][vrd + r * 8 + 4]);
#define ACC8(AI, KC)                                                     \
            acc[AI][0] += (KC) * va.x; acc[AI][1] += (KC) * va.y;        \
            acc[AI][2] += (KC) * va.z; acc[AI][3] += (KC) * va.w;        \
            acc[AI][4] += (KC) * vb.x; acc[AI][5] += (KC) * vb.y;        \
            acc[AI][6] += (KC) * vb.z; acc[AI][7] += (KC) * vb.w;
            ACC8(0, ka.x) ACC8(1, ka.y) ACC8(2, ka.z) ACC8(3, ka.w)
            ACC8(4, kb.x) ACC8(5, kb.y) ACC8(6, kb.z) ACC8(7, kb.w)
#undef ACC8
        }
    }

    // ksum: reduce over lanes sharing oct (bits 3..5)
#pragma unroll
    for (int j = 0; j < 8; ++j) {
        ks[j] += __shfl_xor(ks[j], 8);
        ks[j] += __shfl_xor(ks[j], 16);
        ks[j] += __shfl_xor(ks[j], 32);
    }
    if (lane < 8) {          // lane == oct, one lane per col-octet
#pragma unroll
        for (int j = 0; j < 8; ++j) ksw[wid][lane * 8 + j] = ks[j];
    }

    // cross-wave KV combine (sequential, 4 barriers)
    for (int w = 0; w < 4; ++w) {
        if (wid == w) {
#pragma unroll
            for (int i = 0; i < 8; ++i) {
                float* p = &red[(d0 + i) * 64 + m0];
                float4 a0 = make_float4(acc[i][0], acc[i][1], acc[i][2], acc[i][3]);
                float4 a1 = make_float4(acc[i][4], acc[i][5], acc[i][6], acc[i][7]);
                if (w != 0) {
                    const float4 b0 = *reinterpret_cast<const float4*>(p);
                    const float4 b1 = *reinterpret_cast<const float4*>(p + 4);
                    a0.x += b0.x; a0.y += b0.y; a0.z += b0.z; a0.w += b0.w;
                    a1.x += b1.x; a1.y += b1.y; a1.z += b1.z; a1.w += b1.w;
                }
                *reinterpret_cast<float4*>(p)     = a0;
                *reinterpret_cast<float4*>(p + 4) = a1;
            }
        }
        __syncthreads();
    }

    float* dst = ws + (size_t)(mode ? (chunk * NH_TOT + nh) : nh) * KV_STRIDE;
    if (mode) {
#pragma unroll
        for (int i = 0; i < 4; ++i)
            *reinterpret_cast<float4*>(dst + t * 16 + i * 4) =
                *reinterpret_cast<const float4*>(&red[t * 16 + i * 4]);
        if (t < 64)
            dst[4096 + t] = ksw[0][t] + ksw[1][t] + ksw[2][t] + ksw[3][t];
    } else {
#pragma unroll
        for (int i = 0; i < 16; ++i)
            atomicAdd(dst + t * 16 + i, red[t * 16 + i]);
        if (t < 64)
            atomicAdd(dst + 4096 + t, ksw[0][t] + ksw[1][t] + ksw[2][t] + ksw[3][t]);
    }
}

// ==================== Reduce: sum CH slices into slice 0 ====================
__global__ __launch_bounds__(256) void reduce_kernel(float* __restrict__ ws, int CH)
{
    const int idx = blockIdx.x * 256 + threadIdx.x;
    float s = 0.f;
    for (int c = 0; c < CH; ++c) s += ws[(size_t)c * SLICE + idx];
    ws[idx] = s;
}

// ==================== Pass 2: out = z * (fm(Q) @ KV) ====================
// R2-verbatim (proven). grid (128, 64 nh), block 256.
__global__ __launch_bounds__(256) void out_kernel(
    const float* __restrict__ Q, const float* __restrict__ KVg,
    float* __restrict__ out)
{
    const int t      = threadIdx.x;
    const int lchunk = blockIdx.x;
    const int nh     = blockIdx.y;
    const int n = nh >> 4, h = nh & 15;

    __shared__ float Ql[64 * QSTRIDE];
    __shared__ float KVl[4096];
    __shared__ float Ks[64];
    __shared__ float zl[64];

    const float* kvrow = KVg + (size_t)nh * KV_STRIDE;

#pragma unroll
    for (int j = 0; j < 4; ++j) {
        reinterpret_cast<float4*>(KVl)[t + 256 * j] =
            reinterpret_cast<const float4*>(kvrow)[t + 256 * j];
    }
    if (t < 16) {
        reinterpret_cast<float4*>(Ks)[t] =
            reinterpret_cast<const float4*>(kvrow + 4096)[t];
    }
    __syncthreads();

    const int lane16 = t & 15, grp = t >> 4;
    const int dq = lane16 << 2;
    const float4 ks4 = *reinterpret_cast<const float4*>(&Ks[dq]);
    const size_t qbase = ((size_t)n * L_SEQ + lchunk * 64) * ROWSTRIDE + h * 64;
#pragma unroll
    for (int p = 0; p < 4; ++p) {
        const int rr = p * 16 + grp;
        const float4 qg = *reinterpret_cast<const float4*>(Q + qbase + (size_t)rr * ROWSTRIDE + dq);
        float4 qf;
        qf.x = fm(qg.x); qf.y = fm(qg.y); qf.z = fm(qg.z); qf.w = fm(qg.w);
        *reinterpret_cast<float4*>(&Ql[rr * QSTRIDE + dq]) = qf;
        float dp = qf.x * ks4.x + qf.y * ks4.y + qf.z * ks4.z + qf.w * ks4.w;
        dp += __shfl_xor(dp, 1);
        dp += __shfl_xor(dp, 2);
        dp += __shfl_xor(dp, 4);
        dp += __shfl_xor(dp, 8);
        if (lane16 == 0) zl[rr] = 1.0f / dp + EPSV;
    }
    __syncthreads();

    const int r0 = grp << 2;
    const int c0 = lane16 << 2;
    float acc[4][4] = {};
#pragma unroll 2
    for (int d = 0; d < 64; d += 4) {
        const float4 b0 = *reinterpret_cast<const float4*>(&KVl[(d + 0) * 64 + c0]);
        const float4 b1 = *reinterpret_cast<const float4*>(&KVl[(d + 1) * 64 + c0]);
        const float4 b2 = *reinterpret_cast<const float4*>(&KVl[(d + 2) * 64 + c0]);
        const float4 b3 = *reinterpret_cast<const float4*>(&KVl[(d + 3) * 64 + c0]);
#define DO_ROW(i) do {                                                              \
        const float4 q = *reinterpret_cast<const float4*>(&Ql[(r0 + (i)) * QSTRIDE + d]); \
        acc[i][0] += q.x * b0.x + q.y * b1.x + q.z * b2.x + q.w * b3.x;             \
        acc[i][1] += q.x * b0.y + q.y * b1.y + q.z * b2.y + q.w * b3.y;             \
        acc[i][2] += q.x * b0.z + q.y * b1.z + q.z * b2.z + q.w * b3.z;             \
        acc[i][3] += q.x * b0.w + q.y * b1.w + q.z * b2.w + q.w * b3.w;             \
    } while (0)
        DO_ROW(0); DO_ROW(1); DO_ROW(2); DO_ROW(3);
#undef DO_ROW
    }

#pragma unroll
    for (int i = 0; i < 4; ++i) {
        const float z = zl[r0 + i];
        float4 o;
        o.x = acc[i][0] * z; o.y = acc[i][1] * z; o.z = acc[i][2] * z; o.w = acc[i][3] * z;
        *reinterpret_cast<float4*>(out + qbase + (size_t)(r0 + i) * ROWSTRIDE + c0) = o;
    }
}

extern "C" void kernel_launch(void* const* d_in, const int* in_sizes, int n_in,
                              void* d_out, int out_size, void* d_ws, size_t ws_size,
                              hipStream_t stream) {
    const float* Q = (const float*)d_in[0];
    const float* K = (const float*)d_in[1];
    const float* V = (const float*)d_in[2];
    float* out = (float*)d_out;
    float* ws  = (float*)d_ws;

    const size_t per_slice = (size_t)SLICE * sizeof(float);   // ~1.06 MB
    const bool split = ws_size >= per_slice * CH_SPLIT;

    if (split) {
        kv_pass_kernel<<<dim3(NH_TOT, CH_SPLIT), 256, 0, stream>>>(K, V, ws, 1);
        reduce_kernel<<<SLICE / 256, 256, 0, stream>>>(ws, CH_SPLIT);
    } else {
        hipMemsetAsync(ws, 0, per_slice, stream);
        kv_pass_kernel<<<dim3(NH_TOT, CH_SPLIT), 256, 0, stream>>>(K, V, ws, 0);
    }
    out_kernel<<<dim3(L_SEQ / 64, NH_TOT), 256, 0, stream>>>(Q, ws, out);
}